// Round 7
// baseline (257.059 us; speedup 1.0000x reference)
//
#include <hip/hip_runtime.h>
#include <hip/hip_bf16.h>
#include <stdint.h>

// B=8, T=4096, D=512, OUT=1. M = B*T = 32768.
// cast; fused gates GEMM (ring-2 dbuf, 2 blocks/CU, packed au out); bf16 scan; layer2; LN+proj.

#define MROWS 32768
#define DDIM  512
#define TLEN  4096
#define BSZ   8
#define NCHUNK 64
#define CLEN   64

typedef __attribute__((ext_vector_type(8))) __bf16 bf16x8;
typedef __attribute__((ext_vector_type(4))) float f32x4;
typedef __attribute__((ext_vector_type(4))) unsigned short ushort4_t;
typedef __attribute__((ext_vector_type(2))) unsigned short ushort2_t;

static __device__ __forceinline__ unsigned short f2bf(float f) {
    unsigned int u = __float_as_uint(f);
    u = (u + 0x7FFFu + ((u >> 16) & 1u)) >> 16;   // RNE
    return (unsigned short)u;
}
static __device__ __forceinline__ float bf2f(unsigned short s) {
    return __uint_as_float(((unsigned int)s) << 16);
}
static __device__ __forceinline__ void gload_lds16(const void* gptr, void* ldsp) {
    __builtin_amdgcn_global_load_lds(
        (const __attribute__((address_space(1))) uint32_t*)gptr,
        (__attribute__((address_space(3))) uint32_t*)ldsp,
        16, 0, 0);
}

#define WAITV(n) asm volatile("s_waitcnt vmcnt(" #n ")" ::: "memory")

// ---------------- merged fp32 -> bf16 cast (x + 6 W) ----------------
__global__ __launch_bounds__(256) void cast_all(
    const float4* __restrict__ x,
    const float4* __restrict__ w0, const float4* __restrict__ w1,
    const float4* __restrict__ w2, const float4* __restrict__ w3,
    const float4* __restrict__ w4, const float4* __restrict__ w5,
    ushort4_t* __restrict__ xb, ushort4_t* __restrict__ wb)
{
    int i = blockIdx.x * 256 + threadIdx.x;    // 0 .. 4587519
    float4 v;
    ushort4_t* dst;
    if (i < 4194304) {
        v = x[i];
        dst = xb + i;
    } else {
        int j = i - 4194304;
        int wsel = j >> 16;
        int rem = j & 65535;
        const float4* src = (wsel == 0) ? w0 : (wsel == 1) ? w1 : (wsel == 2) ? w2
                          : (wsel == 3) ? w3 : (wsel == 4) ? w4 : w5;
        v = src[rem];
        dst = wb + j;
    }
    ushort4_t o;
    o.x = f2bf(v.x); o.y = f2bf(v.y); o.z = f2bf(v.z); o.w = f2bf(v.w);
    *dst = o;
}

// ---------------- fused gate GEMM, ring-2 double-buffer ----------------
// 512 thr / 8 waves (2m x 4n), wave tile 64x32; BM=128, BN=128, BK=32; 16 K-steps.
// LDS: 2 buffers x (A[128][32] + BF/BI/BH[128][32]) x 2B = 2 x 32KB = 64KB -> 2 blocks/CU.
// Per K-step: {STAGE t+1 (4 gload_lds, after prev end-barrier protects buffer);
//              vmcnt(4) counted (t+1 stays in flight); barrier;
//              10 ds_read_b128; setprio(1); 24 MFMA; setprio(0); barrier}.
// Swizzle for 64B rows: 16B-chunk cL = cG ^ ((row>>1)&3) -- b128 read's 16 rows
// spread over all 8 bank-groups (2 lanes each = conflict-free floor).
// Staged via pre-swizzled GLOBAL source column; LDS dest stays linear (G21).
__global__ __launch_bounds__(512, 2) void gates_gemm(
    const unsigned short* __restrict__ X,
    const unsigned short* __restrict__ Wf,
    const unsigned short* __restrict__ Wi,
    const unsigned short* __restrict__ Wh,
    const float* __restrict__ bf_, const float* __restrict__ bi_,
    const float* __restrict__ bh_,
    unsigned int* __restrict__ au_out)
{
    __shared__ __align__(16) unsigned short lds[2 * 16384];   // 64 KB

    const int tid  = threadIdx.x;
    const int lane = tid & 63;
    const int wave = tid >> 6;                 // 0..7
    const int wm = wave >> 2, wn = wave & 3;   // 2m x 4n waves of 64x32
    const int lr  = lane & 15;
    const int kgl = lane >> 4;

    // XCD-aware bijective swizzle: 1024 blocks; each XCD gets 32 consecutive by,
    // with the 4 bx-blocks of each by temporally adjacent on that XCD.
    const int w = blockIdx.x;
    const int xcd = w & 7;
    const int s = w >> 3;                      // 0..127
    const int by = xcd * 32 + (s >> 2);        // 0..255
    const int bx = s & 3;                      // 0..3
    const int mblk = by * 128;
    const int nblk = bx * 128;

    // staging: thread -> (row = tid>>2, chunk cL = tid&3); global chunk = cL ^ ((row>>1)&3)
    const int srow = tid >> 2;                                // 0..127
    const int sg   = ((tid & 3) ^ ((srow >> 1) & 3)) << 3;    // swizzled col (bf16 units)
    const int tid8 = tid * 8;                                 // linear LDS dest (ushorts)
    const unsigned short* pA = X  + (size_t)(mblk + srow) * 512 + sg;
    const unsigned short* pF = Wf + (size_t)(nblk + srow) * 512 + sg;
    const unsigned short* pI = Wi + (size_t)(nblk + srow) * 512 + sg;
    const unsigned short* pH = Wh + (size_t)(nblk + srow) * 512 + sg;

    // LDS read offsets (ushort units): row*32 + ((kgl ^ (row>>1)) & 3)*8
    int aoff[4], boff[2];
#pragma unroll
    for (int mi = 0; mi < 4; ++mi) {
        int row = wm * 64 + mi * 16 + lr;
        aoff[mi] = row * 32 + (((kgl ^ (row >> 1)) & 3) << 3);
    }
#pragma unroll
    for (int ni = 0; ni < 2; ++ni) {
        int row = wn * 32 + ni * 16 + lr;
        boff[ni] = row * 32 + (((kgl ^ (row >> 1)) & 3) << 3);
    }

    f32x4 accF[4][2], accI[4][2], accH[4][2];
    const f32x4 zero = {0.f, 0.f, 0.f, 0.f};
#pragma unroll
    for (int mi = 0; mi < 4; ++mi)
#pragma unroll
        for (int ni = 0; ni < 2; ++ni) {
            accF[mi][ni] = zero; accI[mi][ni] = zero; accH[mi][ni] = zero;
        }

#define STAGE(bufp) do { \
    gload_lds16(pA, (bufp) + tid8);          \
    gload_lds16(pF, (bufp) + 4096 + tid8);   \
    gload_lds16(pI, (bufp) + 8192 + tid8);   \
    gload_lds16(pH, (bufp) + 12288 + tid8);  \
    pA += 32; pF += 32; pI += 32; pH += 32; } while (0)

    // prologue: stage tile 0 -> buf0
    STAGE(lds);

#pragma unroll
    for (int t = 0; t < 16; ++t) {
        // stage next tile into the buffer last read at t-1 (protected by t-1's end-barrier)
        if (t < 15) {
            STAGE(lds + ((t + 1) & 1) * 16384);
            WAITV(4);           // tile t's 4 loads done; tile t+1 stays in flight
        } else {
            WAITV(0);
        }
        __builtin_amdgcn_s_barrier();
        __builtin_amdgcn_sched_barrier(0);

        const unsigned short* cb = lds + (t & 1) * 16384;
        bf16x8 af[4];
#pragma unroll
        for (int mi = 0; mi < 4; ++mi)
            af[mi] = *reinterpret_cast<const bf16x8*>(cb + aoff[mi]);
        bf16x8 bF[2], bI[2], bH[2];
#pragma unroll
        for (int ni = 0; ni < 2; ++ni) {
            bF[ni] = *reinterpret_cast<const bf16x8*>(cb + 4096  + boff[ni]);
            bI[ni] = *reinterpret_cast<const bf16x8*>(cb + 8192  + boff[ni]);
            bH[ni] = *reinterpret_cast<const bf16x8*>(cb + 12288 + boff[ni]);
        }
        __builtin_amdgcn_s_setprio(1);
#pragma unroll
        for (int mi = 0; mi < 4; ++mi)
#pragma unroll
            for (int ni = 0; ni < 2; ++ni) {
                accF[mi][ni] = __builtin_amdgcn_mfma_f32_16x16x32_bf16(af[mi], bF[ni], accF[mi][ni], 0, 0, 0);
                accI[mi][ni] = __builtin_amdgcn_mfma_f32_16x16x32_bf16(af[mi], bI[ni], accI[mi][ni], 0, 0, 0);
                accH[mi][ni] = __builtin_amdgcn_mfma_f32_16x16x32_bf16(af[mi], bH[ni], accH[mi][ni], 0, 0, 0);
            }
        __builtin_amdgcn_s_setprio(0);
        __builtin_amdgcn_sched_barrier(0);
        __builtin_amdgcn_s_barrier();   // protects cb from next iteration's STAGE
        __builtin_amdgcn_sched_barrier(0);
    }
#undef STAGE

    // epilogue: col = lane&15 (n), row = kgl*4 + r (m); pack a,u into one u32.
    // a = (1+e^-zi)/(2+e^-zf+e^-zi); i' = (1+e^-zf)/(same); u = i'*zh  (1 rcp total)
#pragma unroll
    for (int ni = 0; ni < 2; ++ni) {
        const int n = nblk + wn * 32 + ni * 16 + lr;
        const float bfv = bf_[n], biv = bi_[n], bhv = bh_[n];
#pragma unroll
        for (int mi = 0; mi < 4; ++mi) {
#pragma unroll
            for (int r = 0; r < 4; ++r) {
                const int m = mblk + wm * 64 + mi * 16 + kgl * 4 + r;
                float zf = accF[mi][ni][r] + bfv;
                float zi = accI[mi][ni][r] + biv;
                float zh = accH[mi][ni][r] + bhv;
                float ef = __expf(-zf);
                float ei = __expf(-zi);
                float inv = __frcp_rn(2.0f + ef + ei);
                float av = (1.0f + ei) * inv;
                float uv = (1.0f + ef) * inv * zh;
                au_out[(size_t)m * 512 + n] =
                    ((unsigned int)f2bf(uv) << 16) | (unsigned int)f2bf(av);
            }
        }
    }
}

// ---------------- chunked scan on packed au ----------------
// gid: d4(7b) | c(6b) | b(3b) -> 65536 threads; row stride = 128 uint4.
__global__ void scan_pass1(const uint4* __restrict__ au,
                           float4* __restrict__ Asum, float4* __restrict__ Usum) {
    int gid = blockIdx.x * 256 + threadIdx.x;    // 0..65535
    int d4 = gid & 127;
    int c  = (gid >> 7) & 63;
    int b  = gid >> 13;
    size_t base = (size_t)(b * TLEN + c * CLEN) * 128 + d4;
    float A[4] = {1.f, 1.f, 1.f, 1.f};
    float h[4] = {0.f, 0.f, 0.f, 0.f};
#pragma unroll 4
    for (int l = 0; l < CLEN; ++l) {
        uint4 v = au[base + (size_t)l * 128];
        unsigned int vv[4] = {v.x, v.y, v.z, v.w};
#pragma unroll
        for (int j = 0; j < 4; ++j) {
            float av = __uint_as_float(vv[j] << 16);
            float uv = __uint_as_float(vv[j] & 0xFFFF0000u);
            A[j] *= av;
            h[j] = av * h[j] + uv;
        }
    }
    size_t s4 = (size_t)(b * NCHUNK + c) * 128 + d4;
    Asum[s4] = make_float4(A[0], A[1], A[2], A[3]);
    Usum[s4] = make_float4(h[0], h[1], h[2], h[3]);
}

__global__ void scan_pass2(const float4* __restrict__ Asum, const float4* __restrict__ Usum,
                           float4* __restrict__ Hinit) {
    int t = blockIdx.x * 256 + threadIdx.x;  // 0..1023
    int d4 = t & 127;
    int b = t >> 7;
    float4 h = {0.f, 0.f, 0.f, 0.f};
    for (int c = 0; c < NCHUNK; ++c) {
        size_t idx = (size_t)(b * NCHUNK + c) * 128 + d4;
        Hinit[idx] = h;
        float4 A = Asum[idx]; float4 U = Usum[idx];
        h.x = A.x * h.x + U.x; h.y = A.y * h.y + U.y;
        h.z = A.z * h.z + U.z; h.w = A.w * h.w + U.w;
    }
}

__global__ void scan_pass3(const uint4* __restrict__ au,
                           const float4* __restrict__ Hinit,
                           ushort4_t* __restrict__ hout) {
    int gid = blockIdx.x * 256 + threadIdx.x;   // 0..65535
    int d4 = gid & 127;
    int c  = (gid >> 7) & 63;
    int b  = gid >> 13;
    size_t base = (size_t)(b * TLEN + c * CLEN) * 128 + d4;
    size_t s4 = (size_t)(b * NCHUNK + c) * 128 + d4;
    float4 h0 = Hinit[s4];
    float h[4] = {h0.x, h0.y, h0.z, h0.w};
#pragma unroll 4
    for (int l = 0; l < CLEN; ++l) {
        size_t idx = base + (size_t)l * 128;
        uint4 v = au[idx];
        unsigned int vv[4] = {v.x, v.y, v.z, v.w};
        ushort4_t o;
#pragma unroll
        for (int j = 0; j < 4; ++j) {
            float av = __uint_as_float(vv[j] << 16);
            float uv = __uint_as_float(vv[j] & 0xFFFF0000u);
            h[j] = av * h[j] + uv;
            o[j] = f2bf(h[j]);
        }
        hout[idx] = o;
    }
}

// ---------------- residual + LayerNorm + out projection ----------------
__global__ __launch_bounds__(256) void final_kernel(
    const float* __restrict__ x, const unsigned short* __restrict__ h1,
    const float* __restrict__ g, const float* __restrict__ bvec,
    const float* __restrict__ Wout, const float* __restrict__ bout,
    float* __restrict__ out)
{
    int row = blockIdx.x;          // 0..32767
    int tid = threadIdx.x;
    size_t base = (size_t)row * 512;
    ushort2_t hv2 = *reinterpret_cast<const ushort2_t*>(h1 + base + tid * 2);
    float2 xv2 = *reinterpret_cast<const float2*>(x + base + tid * 2);
    float r[2];
#pragma unroll
    for (int j = 0; j < 2; ++j) {
        float hv = bf2f(hv2[j]);
        float xv = (j == 0) ? xv2.x : xv2.y;
        if (hv != hv) hv = xv;    // NaN fallback
        r[j] = xv + hv;
    }
    float s = r[0] + r[1];
    float q = r[0] * r[0] + r[1] * r[1];
#pragma unroll
    for (int m = 32; m >= 1; m >>= 1) {
        s += __shfl_xor(s, m);
        q += __shfl_xor(q, m);
    }
    __shared__ float ss[4], sq[4], sp[4];
    int w = tid >> 6, lane = tid & 63;
    if (lane == 0) { ss[w] = s; sq[w] = q; }
    __syncthreads();
    float tot  = ss[0] + ss[1] + ss[2] + ss[3];
    float totq = sq[0] + sq[1] + sq[2] + sq[3];
    float mu = tot * (1.0f / 512.0f);
    float var = totq * (1.0f / 512.0f) - mu * mu;
    float rstd = rsqrtf(var + 1e-5f);
    float p = 0.0f;
#pragma unroll
    for (int j = 0; j < 2; ++j) {
        int d = tid * 2 + j;
        float nv = (r[j] - mu) * rstd * g[d] + bvec[d];
        p += nv * Wout[d];
    }
#pragma unroll
    for (int m = 32; m >= 1; m >>= 1) p += __shfl_xor(p, m);
    if (lane == 0) sp[w] = p;
    __syncthreads();
    if (tid == 0) out[row] = sp[0] + sp[1] + sp[2] + sp[3] + bout[0];
}

extern "C" void kernel_launch(void* const* d_in, const int* in_sizes, int n_in,
                              void* d_out, int out_size, void* d_ws, size_t ws_size,
                              hipStream_t stream) {
    const float* x    = (const float*)d_in[0];
    const float* Wf0  = (const float*)d_in[1];  const float* bf0 = (const float*)d_in[2];
    const float* Wi0  = (const float*)d_in[3];  const float* bi0 = (const float*)d_in[4];
    const float* Wh0  = (const float*)d_in[5];  const float* bh0 = (const float*)d_in[6];
    const float* Wf1  = (const float*)d_in[7];  const float* bf1 = (const float*)d_in[8];
    const float* Wi1  = (const float*)d_in[9];  const float* bi1 = (const float*)d_in[10];
    const float* Wh1  = (const float*)d_in[11]; const float* bh1 = (const float*)d_in[12];
    const float* ln_g = (const float*)d_in[13]; const float* ln_b = (const float*)d_in[14];
    const float* W_out = (const float*)d_in[15]; const float* b_out = (const float*)d_in[16];

    char* ws = (char*)d_ws;
    unsigned short* Xb = (unsigned short*)ws;  ws += (size_t)MROWS * DDIM * 2;   // 32 MB
    unsigned short* Wball = (unsigned short*)ws;
    unsigned short* Wb[6];
    for (int i = 0; i < 6; ++i) { Wb[i] = (unsigned short*)ws; ws += (size_t)DDIM * DDIM * 2; }
    unsigned int* aubuf = (unsigned int*)ws; ws += (size_t)MROWS * DDIM * 4;     // 64 MB packed a|u
    float* Asum = (float*)ws;  ws += (size_t)BSZ * NCHUNK * DDIM * 4;
    float* Usum = (float*)ws;  ws += (size_t)BSZ * NCHUNK * DDIM * 4;
    float* Hinit = (float*)ws; ws += (size_t)BSZ * NCHUNK * DDIM * 4;
    unsigned short* h0b = (unsigned short*)ws; ws += (size_t)MROWS * DDIM * 2;   // 32 MB
    unsigned short* h1b = (unsigned short*)ws; ws += (size_t)MROWS * DDIM * 2;   // 32 MB

    // merged casts
    cast_all<<<17920, 256, 0, stream>>>(
        (const float4*)x, (const float4*)Wf0, (const float4*)Wi0, (const float4*)Wh0,
        (const float4*)Wf1, (const float4*)Wi1, (const float4*)Wh1,
        (ushort4_t*)Xb, (ushort4_t*)Wball);

    // ---- layer 0 ----
    gates_gemm<<<1024, 512, 0, stream>>>(Xb, Wb[0], Wb[1], Wb[2], bf0, bi0, bh0, aubuf);
    scan_pass1<<<256, 256, 0, stream>>>((const uint4*)aubuf, (float4*)Asum, (float4*)Usum);
    scan_pass2<<<4, 256, 0, stream>>>((const float4*)Asum, (const float4*)Usum, (float4*)Hinit);
    scan_pass3<<<256, 256, 0, stream>>>((const uint4*)aubuf, (const float4*)Hinit, (ushort4_t*)h0b);

    // ---- layer 1 ----
    gates_gemm<<<1024, 512, 0, stream>>>(h0b, Wb[3], Wb[4], Wb[5], bf1, bi1, bh1, aubuf);
    scan_pass1<<<256, 256, 0, stream>>>((const uint4*)aubuf, (float4*)Asum, (float4*)Usum);
    scan_pass2<<<4, 256, 0, stream>>>((const float4*)Asum, (const float4*)Usum, (float4*)Hinit);
    scan_pass3<<<256, 256, 0, stream>>>((const uint4*)aubuf, (const float4*)Hinit, (ushort4_t*)h1b);

    // ---- residual + LN + projection ----
    final_kernel<<<MROWS, 256, 0, stream>>>(x, h1b, ln_g, ln_b, W_out, b_out, (float*)d_out);
}

// Round 8
// 246.473 us; speedup vs baseline: 1.0430x; 1.0430x over previous
//
#include <hip/hip_runtime.h>
#include <hip/hip_bf16.h>
#include <stdint.h>

// B=8, T=4096, D=512, OUT=1. M = B*T = 32768.
// cast; fused gates GEMM (ring-2, 16 waves/CU, fused chunk-summary epilogue);
// pass2; pass3 (L0) / pass3+LN+proj fused (L1).

#define MROWS 32768
#define DDIM  512
#define TLEN  4096
#define BSZ   8
#define NCHUNK 64
#define CLEN   64

typedef __attribute__((ext_vector_type(8))) __bf16 bf16x8;
typedef __attribute__((ext_vector_type(4))) float f32x4;
typedef __attribute__((ext_vector_type(4))) unsigned short ushort4_t;

static __device__ __forceinline__ unsigned short f2bf(float f) {
    unsigned int u = __float_as_uint(f);
    u = (u + 0x7FFFu + ((u >> 16) & 1u)) >> 16;   // RNE
    return (unsigned short)u;
}
static __device__ __forceinline__ float bf2f(unsigned short s) {
    return __uint_as_float(((unsigned int)s) << 16);
}
static __device__ __forceinline__ void gload_lds16(const void* gptr, void* ldsp) {
    __builtin_amdgcn_global_load_lds(
        (const __attribute__((address_space(1))) uint32_t*)gptr,
        (__attribute__((address_space(3))) uint32_t*)ldsp,
        16, 0, 0);
}

#define WAITV(n) asm volatile("s_waitcnt vmcnt(" #n ")" ::: "memory")

// ---------------- merged fp32 -> bf16 cast (x + 6 W) ----------------
__global__ __launch_bounds__(256) void cast_all(
    const float4* __restrict__ x,
    const float4* __restrict__ w0, const float4* __restrict__ w1,
    const float4* __restrict__ w2, const float4* __restrict__ w3,
    const float4* __restrict__ w4, const float4* __restrict__ w5,
    ushort4_t* __restrict__ xb, ushort4_t* __restrict__ wb)
{
    int i = blockIdx.x * 256 + threadIdx.x;    // 0 .. 4587519
    float4 v;
    ushort4_t* dst;
    if (i < 4194304) {
        v = x[i];
        dst = xb + i;
    } else {
        int j = i - 4194304;
        int wsel = j >> 16;
        int rem = j & 65535;
        const float4* src = (wsel == 0) ? w0 : (wsel == 1) ? w1 : (wsel == 2) ? w2
                          : (wsel == 3) ? w3 : (wsel == 4) ? w4 : w5;
        v = src[rem];
        dst = wb + j;
    }
    ushort4_t o;
    o.x = f2bf(v.x); o.y = f2bf(v.y); o.z = f2bf(v.z); o.w = f2bf(v.w);
    *dst = o;
}

// ---------------- fused gate GEMM + chunk-summary epilogue ----------------
// 512 thr / 8 waves (4m x 2n), wave tile 32x32; BM=128, BN=64, BK=32; 16 K-steps.
// LDS/buf: A[128][32] 8KB + 3x B[64][32] 12KB = 20KB; ring-2 = 40KB.
// Regs: acc 48 + frags + addr ~110 -> launch_bounds(512,4) => 16 waves/CU (2 blocks).
// Staging: 20 slices x 1KB; waves 0-3 stage 3 slices, waves 4-7 stage 2
// (per-wave counted vmcnt 3/2). Swizzle: chunk cL = cG ^ ((lrow>>1)&3).
// Epilogue additionally emits per-chunk scan summaries (Asum,Usum) --
// wave covers 32 rows = half chunk; kgl-butterfly + LDS pair-combine.
__global__ __launch_bounds__(512, 4) void gates_gemm(
    const unsigned short* __restrict__ X,
    const unsigned short* __restrict__ Wf,
    const unsigned short* __restrict__ Wi,
    const unsigned short* __restrict__ Wh,
    const float* __restrict__ bf_, const float* __restrict__ bi_,
    const float* __restrict__ bh_,
    unsigned int* __restrict__ au_out,
    float* __restrict__ Asum, float* __restrict__ Usum)
{
    __shared__ __align__(16) unsigned short lds[2 * 10240];   // 40 KB

    const int tid  = threadIdx.x;
    const int lane = tid & 63;
    const int wave = tid >> 6;                 // 0..7
    const int wm = wave >> 1;                  // 0..3 : 32-row strip
    const int wn = wave & 1;                   // 0..1 : 32-col strip
    const int lr  = lane & 15;
    const int kgl = lane >> 4;

    // XCD-aware bijective swizzle: 2048 blocks; 8 bx-slices of one by adjacent per XCD.
    const int w = blockIdx.x;
    const int xcd = w & 7;
    const int s = w >> 3;                      // 0..255
    const int by = xcd * 32 + (s >> 3);        // 0..255
    const int bx = s & 7;                      // 0..7
    const int mblk = by * 128;
    const int nblk = bx * 64;

    // staging slices: 0-7 A(16 rows each), 8-11 Wf, 12-15 Wi, 16-19 Wh
    const int r4 = lane >> 2;                  // 0..15 row within slice
    const int c4 = lane & 3;                   // 16B chunk
    const unsigned short *g0, *g1, *g2;
    int o0, o1, o2;
    {
        const int sb = (wave < 4) ? wave * 3 : 12 + (wave - 4) * 2;
        const int sl2 = (wave < 4) ? sb + 2 : sb + 1;
        const int sls[3] = {sb, sb + 1, sl2};
        const unsigned short* gp[3];
        int of[3];
#pragma unroll
        for (int i = 0; i < 3; ++i) {
            int sl = sls[i];
            const unsigned short* src;
            int lrow, grow;
            if (sl < 8)       { src = X;  lrow = sl * 16 + r4;        grow = mblk + lrow; }
            else if (sl < 12) { src = Wf; lrow = (sl - 8) * 16 + r4;  grow = nblk + lrow; }
            else if (sl < 16) { src = Wi; lrow = (sl - 12) * 16 + r4; grow = nblk + lrow; }
            else              { src = Wh; lrow = (sl - 16) * 16 + r4; grow = nblk + lrow; }
            int cg = ((c4 ^ (lrow >> 1)) & 3) << 3;
            gp[i] = src + (size_t)grow * 512 + cg;
            of[i] = sl * 512 + r4 * 32 + c4 * 8;
        }
        g0 = gp[0]; g1 = gp[1]; g2 = gp[2];
        o0 = of[0]; o1 = of[1]; o2 = of[2];
    }

    // LDS read offsets (ushort units)
    int aoff[2], boff[2];
#pragma unroll
    for (int mi = 0; mi < 2; ++mi) {
        int row = wm * 32 + mi * 16 + lr;                 // 0..127
        aoff[mi] = row * 32 + (((kgl ^ (row >> 1)) & 3) << 3);
    }
#pragma unroll
    for (int ni = 0; ni < 2; ++ni) {
        int row = wn * 32 + ni * 16 + lr;                 // 0..63
        boff[ni] = 4096 + row * 32 + (((kgl ^ (row >> 1)) & 3) << 3);
    }

    f32x4 accF[2][2], accI[2][2], accH[2][2];
    const f32x4 zero = {0.f, 0.f, 0.f, 0.f};
#pragma unroll
    for (int mi = 0; mi < 2; ++mi)
#pragma unroll
        for (int ni = 0; ni < 2; ++ni) {
            accF[mi][ni] = zero; accI[mi][ni] = zero; accH[mi][ni] = zero;
        }

#define STAGE(bb) do { \
    gload_lds16(g0, lds + (bb) + o0); \
    gload_lds16(g1, lds + (bb) + o1); \
    if (wave < 4) gload_lds16(g2, lds + (bb) + o2); \
    g0 += 32; g1 += 32; g2 += 32; } while (0)

    STAGE(0);   // tile 0 -> buf0

#pragma unroll
    for (int t = 0; t < 16; ++t) {
        if (t < 15) {
            STAGE(((t + 1) & 1) * 10240);
            if (wave < 4) { WAITV(3); } else { WAITV(2); }
        } else {
            WAITV(0);
        }
        __builtin_amdgcn_s_barrier();
        __builtin_amdgcn_sched_barrier(0);

        const unsigned short* cb = lds + (t & 1) * 10240;
        bf16x8 af[2];
#pragma unroll
        for (int mi = 0; mi < 2; ++mi)
            af[mi] = *reinterpret_cast<const bf16x8*>(cb + aoff[mi]);
        bf16x8 bF[2], bI[2], bH[2];
#pragma unroll
        for (int ni = 0; ni < 2; ++ni) {
            bF[ni] = *reinterpret_cast<const bf16x8*>(cb + boff[ni]);
            bI[ni] = *reinterpret_cast<const bf16x8*>(cb + 2048 + boff[ni]);
            bH[ni] = *reinterpret_cast<const bf16x8*>(cb + 4096 + boff[ni]);
        }
        __builtin_amdgcn_s_setprio(1);
#pragma unroll
        for (int mi = 0; mi < 2; ++mi)
#pragma unroll
            for (int ni = 0; ni < 2; ++ni) {
                accF[mi][ni] = __builtin_amdgcn_mfma_f32_16x16x32_bf16(af[mi], bF[ni], accF[mi][ni], 0, 0, 0);
                accI[mi][ni] = __builtin_amdgcn_mfma_f32_16x16x32_bf16(af[mi], bI[ni], accI[mi][ni], 0, 0, 0);
                accH[mi][ni] = __builtin_amdgcn_mfma_f32_16x16x32_bf16(af[mi], bH[ni], accH[mi][ni], 0, 0, 0);
            }
        __builtin_amdgcn_s_setprio(0);
        __builtin_amdgcn_sched_barrier(0);
        __builtin_amdgcn_s_barrier();
        __builtin_amdgcn_sched_barrier(0);
    }
#undef STAGE

    // ---- epilogue: gates + packed au store + 32-row chunk-partials ----
    // C/D: col = lane&15 (n), row = kgl*4 + r (m).
    float pa[2], pu[2];
#pragma unroll
    for (int ni = 0; ni < 2; ++ni) {
        const int n = nblk + wn * 32 + ni * 16 + lr;
        const float bfv = bf_[n], biv = bi_[n], bhv = bh_[n];
        float ca = 1.f, cu = 0.f;
#pragma unroll
        for (int mi = 0; mi < 2; ++mi) {
            float sa = 1.f, su = 0.f;
#pragma unroll
            for (int r = 0; r < 4; ++r) {
                const int m = mblk + wm * 32 + mi * 16 + kgl * 4 + r;
                float zf = accF[mi][ni][r] + bfv;
                float zi = accI[mi][ni][r] + biv;
                float zh = accH[mi][ni][r] + bhv;
                float ef = __expf(-zf);
                float ei = __expf(-zi);
                float inv = __frcp_rn(2.0f + ef + ei);
                float av = (1.0f + ei) * inv;
                float uv = (1.0f + ef) * inv * zh;
                au_out[(size_t)m * 512 + n] =
                    ((unsigned int)f2bf(uv) << 16) | (unsigned int)f2bf(av);
                sa *= av; su = av * su + uv;      // compose seg with (av,uv)
            }
            // ordered butterfly over kgl (rows ascending with kgl)
            float oa = __shfl_xor(sa, 16), ou = __shfl_xor(su, 16);
            bool up = (lane & 16) != 0;
            float ta = sa * oa;
            float tu = up ? (sa * ou + su) : (oa * su + ou);
            sa = ta; su = tu;
            oa = __shfl_xor(sa, 32); ou = __shfl_xor(su, 32);
            up = (lane & 32) != 0;
            ta = sa * oa;
            tu = up ? (sa * ou + su) : (oa * su + ou);
            sa = ta; su = tu;
            // chunk-partial := chunk-partial then block(mi)
            cu = sa * cu + su; ca = ca * sa;
        }
        pa[ni] = ca; pu[ni] = cu;
    }
    // cross-wave pair combine (wm even = first 32 rows, wm odd = last 32)
    float* sm = (float*)lds;       // sA[4][64] @0, sU[4][64] @256
    if (kgl == 0) {
#pragma unroll
        for (int ni = 0; ni < 2; ++ni) {
            int nl = wn * 32 + ni * 16 + lr;
            sm[wm * 64 + nl] = pa[ni];
            sm[256 + wm * 64 + nl] = pu[ni];
        }
    }
    __syncthreads();
    if (tid < 128) {
        int cl = tid >> 6, nl = tid & 63;
        float a1 = sm[(2 * cl) * 64 + nl],     u1 = sm[256 + (2 * cl) * 64 + nl];
        float a2 = sm[(2 * cl + 1) * 64 + nl], u2 = sm[256 + (2 * cl + 1) * 64 + nl];
        size_t ci = (size_t)(by * 2 + cl) * 512 + nblk + nl;
        Asum[ci] = a1 * a2;
        Usum[ci] = a2 * u1 + u2;
    }
}

// ---------------- chunk-prefix (pass2) ----------------
__global__ void scan_pass2(const float4* __restrict__ Asum, const float4* __restrict__ Usum,
                           float4* __restrict__ Hinit) {
    int t = blockIdx.x * 256 + threadIdx.x;  // 0..1023
    int d4 = t & 127;
    int b = t >> 7;
    float4 h = {0.f, 0.f, 0.f, 0.f};
    for (int c = 0; c < NCHUNK; ++c) {
        size_t idx = (size_t)(b * NCHUNK + c) * 128 + d4;
        Hinit[idx] = h;
        float4 A = Asum[idx]; float4 U = Usum[idx];
        h.x = A.x * h.x + U.x; h.y = A.y * h.y + U.y;
        h.z = A.z * h.z + U.z; h.w = A.w * h.w + U.w;
    }
}

// ---------------- pass3 (layer 0): scan -> bf16 h ----------------
__global__ void scan_pass3(const uint4* __restrict__ au,
                           const float4* __restrict__ Hinit,
                           ushort4_t* __restrict__ hout) {
    int gid = blockIdx.x * 256 + threadIdx.x;   // 0..65535
    int d4 = gid & 127;
    int c  = (gid >> 7) & 63;
    int b  = gid >> 13;
    size_t base = (size_t)(b * TLEN + c * CLEN) * 128 + d4;
    size_t s4 = (size_t)(b * NCHUNK + c) * 128 + d4;
    float4 h0 = Hinit[s4];
    float h[4] = {h0.x, h0.y, h0.z, h0.w};
#pragma unroll 4
    for (int l = 0; l < CLEN; ++l) {
        size_t idx = base + (size_t)l * 128;
        uint4 v = au[idx];
        unsigned int vv[4] = {v.x, v.y, v.z, v.w};
        ushort4_t o;
#pragma unroll
        for (int j = 0; j < 4; ++j) {
            float av = __uint_as_float(vv[j] << 16);
            float uv = __uint_as_float(vv[j] & 0xFFFF0000u);
            h[j] = av * h[j] + uv;
            o[j] = f2bf(h[j]);
        }
        hout[idx] = o;
    }
}

// ---------------- pass3+residual+LN+proj fused (layer 1) ----------------
// block = one (b, chunk): 128 threads own all 512 d (4 each); 64 serial t-steps
// with two 128-wide reductions per step.
__global__ __launch_bounds__(128) void scan3_final(
    const uint4* __restrict__ au, const float4* __restrict__ Hinit,
    const float4* __restrict__ x4,
    const float* __restrict__ g, const float* __restrict__ bvec,
    const float* __restrict__ Wout, const float* __restrict__ bout,
    float* __restrict__ out)
{
    const int blk = blockIdx.x;            // 0..511 = b*64 + c
    const int b = blk >> 6, c = blk & 63;
    const int d4 = threadIdx.x;            // 0..127
    const int lane = threadIdx.x & 63;
    const int wv = threadIdx.x >> 6;

    float4 h0 = Hinit[(size_t)blk * 128 + d4];
    float h[4] = {h0.x, h0.y, h0.z, h0.w};
    float4 g4 = reinterpret_cast<const float4*>(g)[d4];
    float4 b4 = reinterpret_cast<const float4*>(bvec)[d4];
    float4 w4 = reinterpret_cast<const float4*>(Wout)[d4];
    const float ga[4] = {g4.x, g4.y, g4.z, g4.w};
    const float ba[4] = {b4.x, b4.y, b4.z, b4.w};
    const float wa[4] = {w4.x, w4.y, w4.z, w4.w};
    const float bo = bout[0];

    __shared__ float redS[2], redQ[2], redP[2];
    size_t base = ((size_t)b * TLEN + c * CLEN) * 128 + d4;

    for (int l = 0; l < CLEN; ++l) {
        size_t idx = base + (size_t)l * 128;
        uint4 v = au[idx];
        float4 xr = x4[idx];
        const unsigned int vv[4] = {v.x, v.y, v.z, v.w};
        const float xa[4] = {xr.x, xr.y, xr.z, xr.w};
        float r[4];
        float sfl = 0.f, q = 0.f;
#pragma unroll
        for (int j = 0; j < 4; ++j) {
            float av = __uint_as_float(vv[j] << 16);
            float uv = __uint_as_float(vv[j] & 0xFFFF0000u);
            h[j] = av * h[j] + uv;
            float hv = h[j];
            if (hv != hv) hv = xa[j];          // NaN fallback
            float rr = xa[j] + hv;
            r[j] = rr;
            sfl += rr; q += rr * rr;
        }
#pragma unroll
        for (int m = 32; m >= 1; m >>= 1) {
            sfl += __shfl_xor(sfl, m);
            q += __shfl_xor(q, m);
        }
        if (lane == 0) { redS[wv] = sfl; redQ[wv] = q; }
        __syncthreads();
        float st = redS[0] + redS[1];
        float qt = redQ[0] + redQ[1];
        float mu = st * (1.0f / 512.0f);
        float var = qt * (1.0f / 512.0f) - mu * mu;
        float rstd = rsqrtf(var + 1e-5f);
        float p = 0.f;
#pragma unroll
        for (int j = 0; j < 4; ++j)
            p += ((r[j] - mu) * rstd * ga[j] + ba[j]) * wa[j];
#pragma unroll
        for (int m = 32; m >= 1; m >>= 1) p += __shfl_xor(p, m);
        if (lane == 0) redP[wv] = p;
        __syncthreads();
        if (threadIdx.x == 0)
            out[(size_t)b * TLEN + c * CLEN + l] = redP[0] + redP[1] + bo;
    }
}

extern "C" void kernel_launch(void* const* d_in, const int* in_sizes, int n_in,
                              void* d_out, int out_size, void* d_ws, size_t ws_size,
                              hipStream_t stream) {
    const float* x    = (const float*)d_in[0];
    const float* Wf0  = (const float*)d_in[1];  const float* bf0 = (const float*)d_in[2];
    const float* Wi0  = (const float*)d_in[3];  const float* bi0 = (const float*)d_in[4];
    const float* Wh0  = (const float*)d_in[5];  const float* bh0 = (const float*)d_in[6];
    const float* Wf1  = (const float*)d_in[7];  const float* bf1 = (const float*)d_in[8];
    const float* Wi1  = (const float*)d_in[9];  const float* bi1 = (const float*)d_in[10];
    const float* Wh1  = (const float*)d_in[11]; const float* bh1 = (const float*)d_in[12];
    const float* ln_g = (const float*)d_in[13]; const float* ln_b = (const float*)d_in[14];
    const float* W_out = (const float*)d_in[15]; const float* b_out = (const float*)d_in[16];

    char* ws = (char*)d_ws;
    unsigned short* Xb = (unsigned short*)ws;  ws += (size_t)MROWS * DDIM * 2;   // 32 MB
    unsigned short* Wball = (unsigned short*)ws;
    unsigned short* Wb[6];
    for (int i = 0; i < 6; ++i) { Wb[i] = (unsigned short*)ws; ws += (size_t)DDIM * DDIM * 2; }
    unsigned int* aubuf = (unsigned int*)ws; ws += (size_t)MROWS * DDIM * 4;     // 64 MB packed a|u
    float* Asum = (float*)ws;  ws += (size_t)BSZ * NCHUNK * DDIM * 4;            // 1 MB
    float* Usum = (float*)ws;  ws += (size_t)BSZ * NCHUNK * DDIM * 4;
    float* Hinit = (float*)ws; ws += (size_t)BSZ * NCHUNK * DDIM * 4;
    unsigned short* h0b = (unsigned short*)ws; ws += (size_t)MROWS * DDIM * 2;   // 32 MB

    // merged casts
    cast_all<<<17920, 256, 0, stream>>>(
        (const float4*)x, (const float4*)Wf0, (const float4*)Wi0, (const float4*)Wh0,
        (const float4*)Wf1, (const float4*)Wi1, (const float4*)Wh1,
        (ushort4_t*)Xb, (ushort4_t*)Wball);

    // ---- layer 0 ----
    gates_gemm<<<2048, 512, 0, stream>>>(Xb, Wb[0], Wb[1], Wb[2], bf0, bi0, bh0,
                                         aubuf, Asum, Usum);
    scan_pass2<<<4, 256, 0, stream>>>((const float4*)Asum, (const float4*)Usum, (float4*)Hinit);
    scan_pass3<<<256, 256, 0, stream>>>((const uint4*)aubuf, (const float4*)Hinit, (ushort4_t*)h0b);

    // ---- layer 1 ----
    gates_gemm<<<2048, 512, 0, stream>>>(h0b, Wb[3], Wb[4], Wb[5], bf1, bi1, bh1,
                                         aubuf, Asum, Usum);
    scan_pass2<<<4, 256, 0, stream>>>((const float4*)Asum, (const float4*)Usum, (float4*)Hinit);
    scan3_final<<<512, 128, 0, stream>>>((const uint4*)aubuf, (const float4*)Hinit,
                                         (const float4*)x, ln_g, ln_b, W_out, b_out,
                                         (float*)d_out);
}

// Round 9
// 246.198 us; speedup vs baseline: 1.0441x; 1.0011x over previous
//
#include <hip/hip_runtime.h>
#include <hip/hip_bf16.h>
#include <stdint.h>

// B=8, T=4096, D=512, OUT=1. M = B*T = 32768.
// cast; fused gates GEMM (32x32x16 MFMA, 64x32 wave tiles, ring-2, fused chunk
// summaries); pass2; pass3 (L0) / pass3+LN+proj fused (L1).

#define MROWS 32768
#define DDIM  512
#define TLEN  4096
#define BSZ   8
#define NCHUNK 64
#define CLEN   64

typedef __attribute__((ext_vector_type(8))) __bf16 bf16x8;
typedef __attribute__((ext_vector_type(16))) float f32x16;
typedef __attribute__((ext_vector_type(4))) unsigned short ushort4_t;

static __device__ __forceinline__ unsigned short f2bf(float f) {
    unsigned int u = __float_as_uint(f);
    u = (u + 0x7FFFu + ((u >> 16) & 1u)) >> 16;   // RNE
    return (unsigned short)u;
}
static __device__ __forceinline__ float bf2f(unsigned short s) {
    return __uint_as_float(((unsigned int)s) << 16);
}
static __device__ __forceinline__ void gload_lds16(const void* gptr, void* ldsp) {
    __builtin_amdgcn_global_load_lds(
        (const __attribute__((address_space(1))) uint32_t*)gptr,
        (__attribute__((address_space(3))) uint32_t*)ldsp,
        16, 0, 0);
}

#define WAITV(n) asm volatile("s_waitcnt vmcnt(" #n ")" ::: "memory")

// ---------------- merged fp32 -> bf16 cast (x + 6 W) ----------------
__global__ __launch_bounds__(256) void cast_all(
    const float4* __restrict__ x,
    const float4* __restrict__ w0, const float4* __restrict__ w1,
    const float4* __restrict__ w2, const float4* __restrict__ w3,
    const float4* __restrict__ w4, const float4* __restrict__ w5,
    ushort4_t* __restrict__ xb, ushort4_t* __restrict__ wb)
{
    int i = blockIdx.x * 256 + threadIdx.x;    // 0 .. 4587519
    float4 v;
    ushort4_t* dst;
    if (i < 4194304) {
        v = x[i];
        dst = xb + i;
    } else {
        int j = i - 4194304;
        int wsel = j >> 16;
        int rem = j & 65535;
        const float4* src = (wsel == 0) ? w0 : (wsel == 1) ? w1 : (wsel == 2) ? w2
                          : (wsel == 3) ? w3 : (wsel == 4) ? w4 : w5;
        v = src[rem];
        dst = wb + j;
    }
    ushort4_t o;
    o.x = f2bf(v.x); o.y = f2bf(v.y); o.z = f2bf(v.z); o.w = f2bf(v.w);
    *dst = o;
}

// ---------------- fused gate GEMM + chunk-summary epilogue ----------------
// 256 thr / 4 waves (2m x 2n), wave tile 64x32 via 32x32x16 MFMA (2 m-frags x 3 gates,
// acc 6x f32x16 = 96 AGPR). BM=128, BN=64, BK=32; 16 K-steps.
// LDS/buf: A[128][32] 8KB + 3x B[64][32] 4KB = 20KB; ring-2 = 40KB -> 3 blocks/CU.
// Per K-step: {STAGE t+1 (5 gload_lds); vmcnt(5) counted; barrier;
//              10 ds_read_b128; setprio(1); 12 MFMA; setprio(0); barrier}.
// Swizzle (64B rows): 16B-chunk cL = cG ^ ((row>>1)&3); pre-swizzled global src.
// Epilogue: gates -> packed au store + full 64-row chunk summary per wave
// (wave m-strip == one chunk; compose in-lane + shfl_xor(32) per 8-row block).
__global__ __launch_bounds__(256, 3) void gates_gemm(
    const unsigned short* __restrict__ X,
    const unsigned short* __restrict__ Wf,
    const unsigned short* __restrict__ Wi,
    const unsigned short* __restrict__ Wh,
    const float* __restrict__ bf_, const float* __restrict__ bi_,
    const float* __restrict__ bh_,
    unsigned int* __restrict__ au_out,
    float* __restrict__ Asum, float* __restrict__ Usum)
{
    __shared__ __align__(16) unsigned short lds[2 * 10240];   // 40 KB

    const int tid  = threadIdx.x;
    const int lane = tid & 63;
    const int wave = tid >> 6;                 // 0..3
    const int wm = wave >> 1;                  // 0..1 : 64-row strip (= one chunk)
    const int wn = wave & 1;                   // 0..1 : 32-col strip
    const int ln31 = lane & 31;
    const int kh = lane >> 5;                  // k-half for 32x32x16 frags

    // XCD-aware bijective swizzle: 2048 blocks; 8 bx of one by adjacent per XCD.
    const int w = blockIdx.x;
    const int xcd = w & 7;
    const int s = w >> 3;                      // 0..255
    const int by = xcd * 32 + (s >> 3);        // 0..255
    const int bx = s & 7;                      // 0..7
    const int mblk = by * 128;
    const int nblk = bx * 64;

    // staging: thread -> (srow = tid>>2 in 0..63, chunk c4 = tid&3); 5 slices:
    // A rows srow, srow+64; Wf/Wi/Wh row srow. Global col pre-swizzled.
    const int srow = tid >> 2;
    const int c4   = tid & 3;
    const int cg   = ((c4 ^ ((srow >> 1) & 3)) << 3);         // bf16 units
    const int tid8 = tid * 8;                                  // linear LDS dest
    const unsigned short* g0 = X  + (size_t)(mblk + srow) * 512 + cg;
    const unsigned short* g1 = X  + (size_t)(mblk + 64 + srow) * 512 + cg;
    const unsigned short* g2 = Wf + (size_t)(nblk + srow) * 512 + cg;
    const unsigned short* g3 = Wi + (size_t)(nblk + srow) * 512 + cg;
    const unsigned short* g4 = Wh + (size_t)(nblk + srow) * 512 + cg;

    // LDS read offsets (ushort units). A rows local 0..127; B rows local 0..63.
    // chunk c = 2*ks + kh; offset = row*32 + (c ^ ((row>>1)&3))*8.
    int aoff[2][2], boff[2];
#pragma unroll
    for (int mi = 0; mi < 2; ++mi) {
        int row = wm * 64 + mi * 32 + ln31;
#pragma unroll
        for (int ks = 0; ks < 2; ++ks)
            aoff[mi][ks] = row * 32 + (((2 * ks + kh) ^ ((row >> 1) & 3)) << 3);
    }
    {
        int brow = wn * 32 + ln31;
#pragma unroll
        for (int ks = 0; ks < 2; ++ks)
            boff[ks] = brow * 32 + (((2 * ks + kh) ^ ((brow >> 1) & 3)) << 3);
    }

    f32x16 accF[2], accI[2], accH[2];
#pragma unroll
    for (int mi = 0; mi < 2; ++mi) {
#pragma unroll
        for (int e = 0; e < 16; ++e) { accF[mi][e] = 0.f; accI[mi][e] = 0.f; accH[mi][e] = 0.f; }
    }

#define STAGE(bb) do { \
    gload_lds16(g0, lds + (bb) + tid8);            \
    gload_lds16(g1, lds + (bb) + 2048 + tid8);     \
    gload_lds16(g2, lds + (bb) + 4096 + tid8);     \
    gload_lds16(g3, lds + (bb) + 6144 + tid8);     \
    gload_lds16(g4, lds + (bb) + 8192 + tid8);     \
    g0 += 32; g1 += 32; g2 += 32; g3 += 32; g4 += 32; } while (0)

    STAGE(0);   // tile 0 -> buf0

#pragma unroll
    for (int t = 0; t < 16; ++t) {
        if (t < 15) {
            STAGE(((t + 1) & 1) * 10240);   // dest buffer protected by t-1's end barrier
            WAITV(5);                        // tile t's 5 loads done; t+1 in flight
        } else {
            WAITV(0);
        }
        __builtin_amdgcn_s_barrier();
        __builtin_amdgcn_sched_barrier(0);

        const unsigned short* cb = lds + (t & 1) * 10240;
#pragma unroll
        for (int ks = 0; ks < 2; ++ks) {
            bf16x8 af[2];
            af[0] = *reinterpret_cast<const bf16x8*>(cb + aoff[0][ks]);
            af[1] = *reinterpret_cast<const bf16x8*>(cb + aoff[1][ks]);
            bf16x8 bF = *reinterpret_cast<const bf16x8*>(cb + 4096 + boff[ks]);
            bf16x8 bI = *reinterpret_cast<const bf16x8*>(cb + 6144 + boff[ks]);
            bf16x8 bH = *reinterpret_cast<const bf16x8*>(cb + 8192 + boff[ks]);
            __builtin_amdgcn_s_setprio(1);
#pragma unroll
            for (int mi = 0; mi < 2; ++mi) {
                accF[mi] = __builtin_amdgcn_mfma_f32_32x32x16_bf16(af[mi], bF, accF[mi], 0, 0, 0);
                accI[mi] = __builtin_amdgcn_mfma_f32_32x32x16_bf16(af[mi], bI, accI[mi], 0, 0, 0);
                accH[mi] = __builtin_amdgcn_mfma_f32_32x32x16_bf16(af[mi], bH, accH[mi], 0, 0, 0);
            }
            __builtin_amdgcn_s_setprio(0);
        }
        __builtin_amdgcn_sched_barrier(0);
        __builtin_amdgcn_s_barrier();
        __builtin_amdgcn_sched_barrier(0);
    }
#undef STAGE

    // ---- epilogue: gates + packed au + full-chunk summary ----
    // C/D 32x32: col = lane&31 (n), row = (reg&3) + 8*(reg>>2) + 4*(lane>>5).
    const int n = nblk + wn * 32 + ln31;
    const float bfv = bf_[n], biv = bi_[n], bhv = bh_[n];
    const bool up = (lane & 32) != 0;
    float ca = 1.f, cu = 0.f;                  // chunk compose (64 rows, ascending)
#pragma unroll
    for (int mi = 0; mi < 2; ++mi) {
#pragma unroll
        for (int j = 0; j < 4; ++j) {          // 8-row block: rows mi*32 + 8j + 4*hi + r
            float sa = 1.f, su = 0.f;
#pragma unroll
            for (int r = 0; r < 4; ++r) {
                const int reg = 4 * j + r;
                const int m = mblk + wm * 64 + mi * 32 + 8 * j + 4 * kh + r;
                float zf = accF[mi][reg] + bfv;
                float zi = accI[mi][reg] + biv;
                float zh = accH[mi][reg] + bhv;
                float ef = __expf(-zf);
                float ei = __expf(-zi);
                float inv = __frcp_rn(2.0f + ef + ei);
                float av = (1.0f + ei) * inv;
                float uv = (1.0f + ef) * inv * zh;
                au_out[(size_t)m * 512 + n] =
                    ((unsigned int)f2bf(uv) << 16) | (unsigned int)f2bf(av);
                su = av * su + uv; sa *= av;   // compose rows ascending
            }
            // combine hi halves (rows +0..3 then +4..7) via xor-32 exchange
            float oa = __shfl_xor(sa, 32), ou = __shfl_xor(su, 32);
            float ta = sa * oa;
            float tu = up ? (sa * ou + su) : (oa * su + ou);
            // chunk := blk applied after chunk
            cu = ta * cu + tu; ca = ca * ta;
        }
    }
    if (lane < 32) {
        size_t ci = (size_t)(by * 2 + wm) * 512 + n;
        Asum[ci] = ca;
        Usum[ci] = cu;
    }
}

// ---------------- chunk-prefix (pass2) ----------------
__global__ void scan_pass2(const float4* __restrict__ Asum, const float4* __restrict__ Usum,
                           float4* __restrict__ Hinit) {
    int t = blockIdx.x * 256 + threadIdx.x;  // 0..1023
    int d4 = t & 127;
    int b = t >> 7;
    float4 h = {0.f, 0.f, 0.f, 0.f};
    for (int c = 0; c < NCHUNK; ++c) {
        size_t idx = (size_t)(b * NCHUNK + c) * 128 + d4;
        Hinit[idx] = h;
        float4 A = Asum[idx]; float4 U = Usum[idx];
        h.x = A.x * h.x + U.x; h.y = A.y * h.y + U.y;
        h.z = A.z * h.z + U.z; h.w = A.w * h.w + U.w;
    }
}

// ---------------- pass3 (layer 0): scan -> bf16 h ----------------
__global__ void scan_pass3(const uint4* __restrict__ au,
                           const float4* __restrict__ Hinit,
                           ushort4_t* __restrict__ hout) {
    int gid = blockIdx.x * 256 + threadIdx.x;   // 0..65535
    int d4 = gid & 127;
    int c  = (gid >> 7) & 63;
    int b  = gid >> 13;
    size_t base = (size_t)(b * TLEN + c * CLEN) * 128 + d4;
    size_t s4 = (size_t)(b * NCHUNK + c) * 128 + d4;
    float4 h0 = Hinit[s4];
    float h[4] = {h0.x, h0.y, h0.z, h0.w};
#pragma unroll 4
    for (int l = 0; l < CLEN; ++l) {
        size_t idx = base + (size_t)l * 128;
        uint4 v = au[idx];
        unsigned int vv[4] = {v.x, v.y, v.z, v.w};
        ushort4_t o;
#pragma unroll
        for (int j = 0; j < 4; ++j) {
            float av = __uint_as_float(vv[j] << 16);
            float uv = __uint_as_float(vv[j] & 0xFFFF0000u);
            h[j] = av * h[j] + uv;
            o[j] = f2bf(h[j]);
        }
        hout[idx] = o;
    }
}

// ---------------- pass3+residual+LN+proj fused (layer 1) ----------------
__global__ __launch_bounds__(128) void scan3_final(
    const uint4* __restrict__ au, const float4* __restrict__ Hinit,
    const float4* __restrict__ x4,
    const float* __restrict__ g, const float* __restrict__ bvec,
    const float* __restrict__ Wout, const float* __restrict__ bout,
    float* __restrict__ out)
{
    const int blk = blockIdx.x;            // 0..511 = b*64 + c
    const int b = blk >> 6, c = blk & 63;
    const int d4 = threadIdx.x;            // 0..127
    const int lane = threadIdx.x & 63;
    const int wv = threadIdx.x >> 6;

    float4 h0 = Hinit[(size_t)blk * 128 + d4];
    float h[4] = {h0.x, h0.y, h0.z, h0.w};
    float4 g4 = reinterpret_cast<const float4*>(g)[d4];
    float4 b4 = reinterpret_cast<const float4*>(bvec)[d4];
    float4 w4 = reinterpret_cast<const float4*>(Wout)[d4];
    const float ga[4] = {g4.x, g4.y, g4.z, g4.w};
    const float ba[4] = {b4.x, b4.y, b4.z, b4.w};
    const float wa[4] = {w4.x, w4.y, w4.z, w4.w};
    const float bo = bout[0];

    __shared__ float redS[2], redQ[2], redP[2];
    size_t base = ((size_t)b * TLEN + c * CLEN) * 128 + d4;

    for (int l = 0; l < CLEN; ++l) {
        size_t idx = base + (size_t)l * 128;
        uint4 v = au[idx];
        float4 xr = x4[idx];
        const unsigned int vv[4] = {v.x, v.y, v.z, v.w};
        const float xa[4] = {xr.x, xr.y, xr.z, xr.w};
        float r[4];
        float sfl = 0.f, q = 0.f;
#pragma unroll
        for (int j = 0; j < 4; ++j) {
            float av = __uint_as_float(vv[j] << 16);
            float uv = __uint_as_float(vv[j] & 0xFFFF0000u);
            h[j] = av * h[j] + uv;
            float hv = h[j];
            if (hv != hv) hv = xa[j];          // NaN fallback
            float rr = xa[j] + hv;
            r[j] = rr;
            sfl += rr; q += rr * rr;
        }
#pragma unroll
        for (int m = 32; m >= 1; m >>= 1) {
            sfl += __shfl_xor(sfl, m);
            q += __shfl_xor(q, m);
        }
        if (lane == 0) { redS[wv] = sfl; redQ[wv] = q; }
        __syncthreads();
        float st = redS[0] + redS[1];
        float qt = redQ[0] + redQ[1];
        float mu = st * (1.0f / 512.0f);
        float var = qt * (1.0f / 512.0f) - mu * mu;
        float rstd = rsqrtf(var + 1e-5f);
        float p = 0.f;
#pragma unroll
        for (int j = 0; j < 4; ++j)
            p += ((r[j] - mu) * rstd * ga[j] + ba[j]) * wa[j];
#pragma unroll
        for (int m = 32; m >= 1; m >>= 1) p += __shfl_xor(p, m);
        if (lane == 0) redP[wv] = p;
        __syncthreads();
        if (threadIdx.x == 0)
            out[(size_t)b * TLEN + c * CLEN + l] = redP[0] + redP[1] + bo;
    }
}

extern "C" void kernel_launch(void* const* d_in, const int* in_sizes, int n_in,
                              void* d_out, int out_size, void* d_ws, size_t ws_size,
                              hipStream_t stream) {
    const float* x    = (const float*)d_in[0];
    const float* Wf0  = (const float*)d_in[1];  const float* bf0 = (const float*)d_in[2];
    const float* Wi0  = (const float*)d_in[3];  const float* bi0 = (const float*)d_in[4];
    const float* Wh0  = (const float*)d_in[5];  const float* bh0 = (const float*)d_in[6];
    const float* Wf1  = (const float*)d_in[7];  const float* bf1 = (const float*)d_in[8];
    const float* Wi1  = (const float*)d_in[9];  const float* bi1 = (const float*)d_in[10];
    const float* Wh1  = (const float*)d_in[11]; const float* bh1 = (const float*)d_in[12];
    const float* ln_g = (const float*)d_in[13]; const float* ln_b = (const float*)d_in[14];
    const float* W_out = (const float*)d_in[15]; const float* b_out = (const float*)d_in[16];

    char* ws = (char*)d_ws;
    unsigned short* Xb = (unsigned short*)ws;  ws += (size_t)MROWS * DDIM * 2;   // 32 MB
    unsigned short* Wball = (unsigned short*)ws;
    unsigned short* Wb[6];
    for (int i = 0; i < 6; ++i) { Wb[i] = (unsigned short*)ws; ws += (size_t)DDIM * DDIM * 2; }
    unsigned int* aubuf = (unsigned int*)ws; ws += (size_t)MROWS * DDIM * 4;     // 64 MB packed a|u
    float* Asum = (float*)ws;  ws += (size_t)BSZ * NCHUNK * DDIM * 4;            // 1 MB
    float* Usum = (float*)ws;  ws += (size_t)BSZ * NCHUNK * DDIM * 4;
    float* Hinit = (float*)ws; ws += (size_t)BSZ * NCHUNK * DDIM * 4;
    unsigned short* h0b = (unsigned short*)ws; ws += (size_t)MROWS * DDIM * 2;   // 32 MB

    // merged casts
    cast_all<<<17920, 256, 0, stream>>>(
        (const float4*)x, (const float4*)Wf0, (const float4*)Wi0, (const float4*)Wh0,
        (const float4*)Wf1, (const float4*)Wi1, (const float4*)Wh1,
        (ushort4_t*)Xb, (ushort4_t*)Wball);

    // ---- layer 0 ----
    gates_gemm<<<2048, 256, 0, stream>>>(Xb, Wb[0], Wb[1], Wb[2], bf0, bi0, bh0,
                                         aubuf, Asum, Usum);
    scan_pass2<<<4, 256, 0, stream>>>((const float4*)Asum, (const float4*)Usum, (float4*)Hinit);
    scan_pass3<<<256, 256, 0, stream>>>((const uint4*)aubuf, (const float4*)Hinit, (ushort4_t*)h0b);

    // ---- layer 1 ----
    gates_gemm<<<2048, 256, 0, stream>>>(h0b, Wb[3], Wb[4], Wb[5], bf1, bi1, bh1,
                                         aubuf, Asum, Usum);
    scan_pass2<<<4, 256, 0, stream>>>((const float4*)Asum, (const float4*)Usum, (float4*)Hinit);
    scan3_final<<<512, 128, 0, stream>>>((const uint4*)aubuf, (const float4*)Hinit,
                                         (const float4*)x, ln_g, ln_b, W_out, b_out,
                                         (float*)d_out);
}